// Round 5
// baseline (322.179 us; speedup 1.0000x reference)
//
#include <hip/hip_runtime.h>
#include <hip/hip_bf16.h>

#define M_DIM 8192
#define N_DIM 4096
#define K_DIM 4096
#define NT (K_DIM / 32)   // 128 K-tiles of BK=32

typedef __bf16 bf16x8 __attribute__((ext_vector_type(8)));
typedef float f32x4 __attribute__((ext_vector_type(4)));
typedef unsigned short ushort8v __attribute__((ext_vector_type(8)));

typedef const __attribute__((address_space(1))) void gv_t;
typedef __attribute__((address_space(3))) void lv_t;

static __device__ __forceinline__ unsigned short f2bf(float f) {
  unsigned u = __builtin_bit_cast(unsigned, f);
  u += 0x7fffu + ((u >> 16) & 1u);
  return (unsigned short)(u >> 16);
}

// ---------------- pre-pass 1: inverse permutation ----------------
__global__ void k_pinv(const int* __restrict__ ci, int* __restrict__ pinv) {
  int k = blockIdx.x * 256 + threadIdx.x;
  if (k < K_DIM) pinv[ci[k]] = k;
}

// ---------------- pre-pass 2: x fp32 -> bf16 ----------------
__global__ void k_cvt(const float* __restrict__ x, unsigned short* __restrict__ xb) {
  const long n4 = (long)M_DIM * K_DIM / 4;
  for (long i = (long)blockIdx.x * 256 + threadIdx.x; i < n4; i += 2048L * 256) {
    float4 v = *(const float4*)(x + i * 4);
    ushort4 o;
    o.x = f2bf(v.x); o.y = f2bf(v.y); o.z = f2bf(v.z); o.w = f2bf(v.w);
    *(ushort4*)(xb + i * 4) = o;
  }
}

// ---------------- pre-pass 3: dequant + permute + transpose ----------------
// w2t[n][c] = (float)w[pinv[c]][n] * scales[pinv[c]>>7][n]  as bf16, [N][K]
__global__ void k_w2t(const int* __restrict__ w, const float* __restrict__ scales,
                      const int* __restrict__ pinv, unsigned short* __restrict__ w2t) {
  __shared__ int tile[64 * 68];
  __shared__ int grp[64];
  __shared__ int krow[64];
  const int n0 = blockIdx.x * 64;
  const int c0 = blockIdx.y * 64;
  const int t = threadIdx.x;
  if (t < 64) {
    int kk = pinv[c0 + t];
    krow[t] = kk;
    grp[t] = kk >> 7;
  }
  __syncthreads();
  {
    const int ci = t >> 2, q = t & 3;
    const int kk = krow[ci];
    const int* src = w + (long)kk * N_DIM + n0 + q * 16;
#pragma unroll
    for (int j = 0; j < 4; ++j) {
      int4 v = *(const int4*)(src + j * 4);
      *(int4*)&tile[ci * 68 + q * 16 + j * 4] = v;
    }
  }
  __syncthreads();
  {
    const int nj = t >> 2, cq = t & 3;
    const int n = n0 + nj;
    unsigned short outv[16];
#pragma unroll
    for (int i = 0; i < 16; ++i) {
      int cii = cq * 16 + i;
      float f = (float)tile[cii * 68 + nj] * scales[grp[cii] * N_DIM + n];
      outv[i] = f2bf(f);
    }
    unsigned short* dst = w2t + (long)n * K_DIM + c0 + cq * 16;
    *(ushort8v*)(dst)     = *(ushort8v*)&outv[0];
    *(ushort8v*)(dst + 8) = *(ushort8v*)&outv[8];
  }
}

// ---------------- main GEMM: 256x256, BK=32, 8 waves, 4-buffer distance-3 pipeline ----------------
// 4 LDS buffers x 32 KiB = 128 KiB. Per tile t (2 phases):
//  q0: stage tile t+3 (4 loads); read A-hi(t); MFMA q0; vmcnt(8); barrier (publish t+1)
//  q1: read A-lo(t+1); MFMA q1; read B(t+1); barrier (protect buf[t&3] for restage)
// Publish wait covers loads issued 4-6 phases earlier -> no HBM-latency stall.
__global__ __launch_bounds__(512, 2) void k_gemm(const unsigned short* __restrict__ A,
                                                 const unsigned short* __restrict__ Bt,
                                                 const float* __restrict__ bias,
                                                 float* __restrict__ C) {
  __shared__ __attribute__((aligned(16))) char lds[4 * 32768];   // 128 KiB

  const int bid = blockIdx.x;                  // 512 blocks, %8==0 -> bijective
  const int swz = (bid & 7) * 64 + (bid >> 3);
  const int by = swz >> 4;                     // 0..31
  const int bx = swz & 15;                     // 0..15

  const int tid = threadIdx.x;
  const int l = tid & 63;
  const int w = tid >> 6;
  const int wr = w >> 2;
  const int wc = w & 3;
  const int r4 = l & 15;
  const int kb = (l >> 4) << 4;
  const int rmask = (r4 & 14) << 3;

  // staging sources (pre-swizzled global addrs; LDS dest linear) — verified 0-conflict
  const int wmask = ((tid >> 3) & 7) << 4;
  const char* srcA[2];
  const char* srcB[2];
  {
    const char* Ab = (const char*)A + (size_t)(by * 256) * (K_DIM * 2);
    const char* Bb = (const char*)Bt + (size_t)(bx * 256) * (K_DIM * 2);
#pragma unroll
    for (int j = 0; j < 2; ++j) {
      int L = j * 8192 + tid * 16;
      int lg = L ^ wmask;
      int row = lg >> 6, kbo = lg & 63;
      srcA[j] = Ab + (size_t)row * (K_DIM * 2) + kbo;
      srcB[j] = Bb + (size_t)row * (K_DIM * 2) + kbo;
    }
  }
  const int stgoff = tid * 16;

  const int aoff = (((wr * 128 + r4) << 6) + kb) ^ rmask;
  const int boff = (((wc * 64  + r4) << 6) + kb) ^ rmask;

  f32x4 acc[8][4];
  const f32x4 z = {0.f, 0.f, 0.f, 0.f};
#pragma unroll
  for (int mi = 0; mi < 8; ++mi)
#pragma unroll
    for (int ni = 0; ni < 4; ++ni) acc[mi][ni] = z;

  // ---- prologue: stage tiles 0,1,2 -> buf0,1,2 (12 loads) ----
#pragma unroll
  for (int tt = 0; tt < 3; ++tt) {
    char* ab = lds + tt * 32768;
    char* bb = ab + 16384;
#pragma unroll
    for (int j = 0; j < 2; ++j)
      __builtin_amdgcn_global_load_lds((gv_t*)(srcA[j] + tt * 64), (lv_t*)(ab + j * 8192 + stgoff), 16, 0, 0);
#pragma unroll
    for (int j = 0; j < 2; ++j)
      __builtin_amdgcn_global_load_lds((gv_t*)(srcB[j] + tt * 64), (lv_t*)(bb + j * 8192 + stgoff), 16, 0, 0);
  }
  asm volatile("s_waitcnt vmcnt(8)" ::: "memory");   // tile 0 landed (1,2 in flight)
  __builtin_amdgcn_sched_barrier(0);
  __builtin_amdgcn_s_barrier();
  __builtin_amdgcn_sched_barrier(0);

  // q0 operands of tile 0
  bf16x8 fA[4], fB[4], gA1[4];
#pragma unroll
  for (int mi = 0; mi < 4; ++mi) fA[mi] = *(const bf16x8*)(lds + aoff + mi * 1024);
#pragma unroll
  for (int ni = 0; ni < 4; ++ni) fB[ni] = *(const bf16x8*)(lds + 16384 + boff + ni * 1024);

  for (int t = 0; t < NT; ++t) {
    char* Ac = lds + (t & 3) * 32768;
    char* Bc = Ac + 16384;
    char* An = lds + ((t + 1) & 3) * 32768;
    char* Bn = An + 16384;
    char* As = lds + ((t + 3) & 3) * 32768;
    char* Bs = As + 16384;

    // ======== q0: stage t+3; read A-hi(t); MFMA q0 ========
    if (t + 3 < NT) {
      const long ko = (long)(t + 3) * 64;
      __builtin_amdgcn_global_load_lds((gv_t*)(srcA[0] + ko), (lv_t*)(As + stgoff), 16, 0, 0);
      __builtin_amdgcn_global_load_lds((gv_t*)(srcA[1] + ko), (lv_t*)(As + 8192 + stgoff), 16, 0, 0);
      __builtin_amdgcn_global_load_lds((gv_t*)(srcB[0] + ko), (lv_t*)(Bs + stgoff), 16, 0, 0);
      __builtin_amdgcn_global_load_lds((gv_t*)(srcB[1] + ko), (lv_t*)(Bs + 8192 + stgoff), 16, 0, 0);
    }
#pragma unroll
    for (int mi = 0; mi < 4; ++mi)
      gA1[mi] = *(const bf16x8*)(Ac + aoff + 4096 + mi * 1024);

    __builtin_amdgcn_s_setprio(1);
#pragma unroll
    for (int mi = 0; mi < 4; ++mi)
#pragma unroll
      for (int ni = 0; ni < 4; ++ni)
        acc[mi][ni] = __builtin_amdgcn_mfma_f32_16x16x32_bf16(fA[mi], fB[ni], acc[mi][ni], 0, 0, 0);
    __builtin_amdgcn_s_setprio(0);

    if (t < NT - 3)       asm volatile("s_waitcnt vmcnt(8)" ::: "memory");
    else if (t == NT - 3) asm volatile("s_waitcnt vmcnt(4)" ::: "memory");
    else                  asm volatile("s_waitcnt vmcnt(0)" ::: "memory");
    __builtin_amdgcn_sched_barrier(0);
    __builtin_amdgcn_s_barrier();                    // publish buf[t+1]
    __builtin_amdgcn_sched_barrier(0);

    // ======== q1: read A-lo(t+1); MFMA q1; read B(t+1) ========
    if (t + 1 < NT) {
#pragma unroll
      for (int mi = 0; mi < 4; ++mi)
        fA[mi] = *(const bf16x8*)(An + aoff + mi * 1024);
    }

    __builtin_amdgcn_s_setprio(1);
#pragma unroll
    for (int mi = 0; mi < 4; ++mi)
#pragma unroll
      for (int ni = 0; ni < 4; ++ni)
        acc[4 + mi][ni] = __builtin_amdgcn_mfma_f32_16x16x32_bf16(gA1[mi], fB[ni], acc[4 + mi][ni], 0, 0, 0);
    __builtin_amdgcn_s_setprio(0);

    if (t + 1 < NT) {
#pragma unroll
      for (int ni = 0; ni < 4; ++ni)
        fB[ni] = *(const bf16x8*)(Bn + boff + ni * 1024);
    }
    __builtin_amdgcn_sched_barrier(0);
    __builtin_amdgcn_s_barrier();                    // protect buf[t&3] for restage at q0(t+1)
    __builtin_amdgcn_sched_barrier(0);
  }

  // ---- epilogue: C/D layout col=l&15, row=(l>>4)*4+reg ----
  const int row0 = by * 256 + wr * 128 + ((l >> 4) << 2);
  const int col0 = bx * 256 + wc * 64 + r4;
#pragma unroll
  for (int ni = 0; ni < 4; ++ni) {
    const int col = col0 + ni * 16;
    const float bv = bias[col];
#pragma unroll
    for (int mi = 0; mi < 8; ++mi) {
#pragma unroll
      for (int r = 0; r < 4; ++r)
        C[(size_t)(row0 + mi * 16 + r) * N_DIM + col] = acc[mi][ni][r] + bv;
    }
  }
}

// ---------------- fallback ----------------
__global__ void k_fallback(const float* __restrict__ x, const float* __restrict__ scales,
                           const float* __restrict__ bias, const int* __restrict__ w,
                           const int* __restrict__ ci, float* __restrict__ out) {
  const int n = blockIdx.x * 256 + threadIdx.x;
  const int m0 = blockIdx.y * 32;
  float acc[32];
#pragma unroll
  for (int i = 0; i < 32; ++i) acc[i] = 0.f;
  for (int k = 0; k < K_DIM; ++k) {
    int c = ci[k];
    float wv = (float)w[(long)k * N_DIM + n] * scales[(k >> 7) * N_DIM + n];
#pragma unroll 8
    for (int mm = 0; mm < 32; ++mm)
      acc[mm] += x[(long)(m0 + mm) * K_DIM + c] * wv;
  }
  float bv = bias[n];
  for (int mm = 0; mm < 32; ++mm)
    out[(long)(m0 + mm) * N_DIM + n] = acc[mm] + bv;
}

extern "C" void kernel_launch(void* const* d_in, const int* in_sizes, int n_in,
                              void* d_out, int out_size, void* d_ws, size_t ws_size,
                              hipStream_t stream) {
  const float* x      = (const float*)d_in[0];
  const float* scales = (const float*)d_in[1];
  const float* bias   = (const float*)d_in[2];
  const int*   wq     = (const int*)d_in[3];
  const int*   ci     = (const int*)d_in[4];
  float* out = (float*)d_out;

  const size_t xb_bytes  = (size_t)M_DIM * K_DIM * 2;
  const size_t w2t_bytes = (size_t)N_DIM * K_DIM * 2;
  const size_t need = xb_bytes + w2t_bytes + (size_t)K_DIM * 4;

  if (ws_size < need) {
    k_fallback<<<dim3(N_DIM / 256, M_DIM / 32), 256, 0, stream>>>(x, scales, bias, wq, ci, out);
    return;
  }

  unsigned short* xb  = (unsigned short*)d_ws;
  unsigned short* w2t = (unsigned short*)((char*)d_ws + xb_bytes);
  int* pinv           = (int*)((char*)d_ws + xb_bytes + w2t_bytes);

  k_pinv<<<K_DIM / 256, 256, 0, stream>>>(ci, pinv);
  k_cvt<<<2048, 256, 0, stream>>>(x, xb);
  k_w2t<<<dim3(N_DIM / 64, K_DIM / 64), 256, 0, stream>>>(wq, scales, pinv, w2t);
  k_gemm<<<(M_DIM / 256) * (N_DIM / 256), 512, 0, stream>>>(xb, w2t, bias, out);
}

// Round 6
// 298.803 us; speedup vs baseline: 1.0782x; 1.0782x over previous
//
#include <hip/hip_runtime.h>
#include <hip/hip_bf16.h>

#define M_DIM 8192
#define N_DIM 4096
#define K_DIM 4096
#define NITER 32   // 32 iters x 2 K-tiles(64) = 4096

typedef __bf16 bf16x8 __attribute__((ext_vector_type(8)));
typedef float f32x4 __attribute__((ext_vector_type(4)));
typedef unsigned short ushort8v __attribute__((ext_vector_type(8)));

typedef const __attribute__((address_space(1))) void gv_t;
typedef __attribute__((address_space(3))) void lv_t;

static __device__ __forceinline__ unsigned short f2bf(float f) {
  unsigned u = __builtin_bit_cast(unsigned, f);
  u += 0x7fffu + ((u >> 16) & 1u);
  return (unsigned short)(u >> 16);
}

// ---------------- pre-pass 1: inverse permutation ----------------
__global__ void k_pinv(const int* __restrict__ ci, int* __restrict__ pinv) {
  int k = blockIdx.x * 256 + threadIdx.x;
  if (k < K_DIM) pinv[ci[k]] = k;
}

// ---------------- pre-pass 2: x fp32 -> bf16 ----------------
__global__ void k_cvt(const float* __restrict__ x, unsigned short* __restrict__ xb) {
  const long n4 = (long)M_DIM * K_DIM / 4;
  for (long i = (long)blockIdx.x * 256 + threadIdx.x; i < n4; i += 2048L * 256) {
    float4 v = *(const float4*)(x + i * 4);
    ushort4 o;
    o.x = f2bf(v.x); o.y = f2bf(v.y); o.z = f2bf(v.z); o.w = f2bf(v.w);
    *(ushort4*)(xb + i * 4) = o;
  }
}

// ---------------- pre-pass 3: dequant + permute + transpose ----------------
__global__ void k_w2t(const int* __restrict__ w, const float* __restrict__ scales,
                      const int* __restrict__ pinv, unsigned short* __restrict__ w2t) {
  __shared__ int tile[64 * 68];
  __shared__ int grp[64];
  __shared__ int krow[64];
  const int n0 = blockIdx.x * 64;
  const int c0 = blockIdx.y * 64;
  const int t = threadIdx.x;
  if (t < 64) {
    int kk = pinv[c0 + t];
    krow[t] = kk;
    grp[t] = kk >> 7;
  }
  __syncthreads();
  {
    const int ci = t >> 2, q = t & 3;
    const int kk = krow[ci];
    const int* src = w + (long)kk * N_DIM + n0 + q * 16;
#pragma unroll
    for (int j = 0; j < 4; ++j) {
      int4 v = *(const int4*)(src + j * 4);
      *(int4*)&tile[ci * 68 + q * 16 + j * 4] = v;
    }
  }
  __syncthreads();
  {
    const int nj = t >> 2, cq = t & 3;
    const int n = n0 + nj;
    unsigned short outv[16];
#pragma unroll
    for (int i = 0; i < 16; ++i) {
      int cii = cq * 16 + i;
      float f = (float)tile[cii * 68 + nj] * scales[grp[cii] * N_DIM + n];
      outv[i] = f2bf(f);
    }
    unsigned short* dst = w2t + (long)n * K_DIM + c0 + cq * 16;
    *(ushort8v*)(dst)     = *(ushort8v*)&outv[0];
    *(ushort8v*)(dst + 8) = *(ushort8v*)&outv[8];
  }
}

// ---------------- main GEMM: 256x256, BK=64, 8 waves, m201-style 8-phase ----------------
// buf0 = even K-tile, buf1 = odd (static). Phase: {ds_read own operands; 2 gload;
// barrier; lgkmcnt(0); setprio; 16 MFMA; setprio; [vmcnt(4) gate]; barrier}.
// Staging: P0:B1j23 P1:A1j02 P2:A1j13 P3:B0j01 P4:B0j23 P5:A0j02 P6:A0j13 P7:B1j01.
// Gates vmcnt(4) at ends of P0,P3,P4,P7 (audited; last iter P3-end -> vmcnt(0)).
#define RD_A4(base) do { const char* _b=(const char*)(base); \
  af[0]=*(const bf16x8*)(_b); af[1]=*(const bf16x8*)(_b+2048); \
  af[2]=*(const bf16x8*)(_b+4096); af[3]=*(const bf16x8*)(_b+6144); } while(0)
#define RD_B4(base) do { const char* _b=(const char*)(base); \
  bf[0]=*(const bf16x8*)(_b); bf[1]=*(const bf16x8*)(_b+2048); \
  bf[2]=*(const bf16x8*)(_b+4096); bf[3]=*(const bf16x8*)(_b+6144); } while(0)
#define MFMA16(o) do { \
  _Pragma("unroll") for (int mi = 0; mi < 4; ++mi) \
  _Pragma("unroll") for (int ni = 0; ni < 4; ++ni) \
    acc[(o)+mi][ni] = __builtin_amdgcn_mfma_f32_16x16x32_bf16(af[mi], bf[ni], acc[(o)+mi][ni], 0, 0, 0); \
  } while(0)
#define GL(s, d) __builtin_amdgcn_global_load_lds((gv_t*)(s), (lv_t*)(d), 16, 0, 0)
#define BAR_IN() do { __builtin_amdgcn_s_barrier(); \
  asm volatile("s_waitcnt lgkmcnt(0)" ::: "memory"); \
  __builtin_amdgcn_sched_barrier(0); } while(0)
#define BAR_OUT() do { __builtin_amdgcn_sched_barrier(0); \
  __builtin_amdgcn_s_barrier(); __builtin_amdgcn_sched_barrier(0); } while(0)
#define VM4() asm volatile("s_waitcnt vmcnt(4)" ::: "memory")

__global__ __launch_bounds__(512, 2) void k_gemm(const unsigned short* __restrict__ A,
                                                 const unsigned short* __restrict__ Bt,
                                                 const float* __restrict__ bias,
                                                 float* __restrict__ C) {
  __shared__ __attribute__((aligned(16))) char lds[131072];   // 128 KiB
  char* A0 = lds;             // buf0 A (32K)
  char* B0 = lds + 32768;     // buf0 B
  char* A1 = lds + 65536;     // buf1 A
  char* B1 = lds + 98304;     // buf1 B

  const int bid = blockIdx.x;                  // 512 blocks, %8==0 -> bijective
  const int swz = (bid & 7) * 64 + (bid >> 3);
  const int by = swz >> 4;                     // 0..31
  const int bx = swz & 15;                     // 0..15

  const int tid = threadIdx.x;
  const int l = tid & 63;
  const int w = tid >> 6;
  const int wr = w >> 2;        // 0..1
  const int wc = w & 3;         // 0..3
  const int r4 = l & 15;
  const int kb = (l >> 4) << 4;               // 0,16,32,48

  // staging sources (pre-swizzled; LDS dest linear). Rows of 128B; load j = rows [64j,64j+64).
  const int wmask = ((tid >> 3) & 7) << 4;
  const int kbo = ((tid & 7) * 16) ^ wmask;
  const char* srcA = (const char*)A + (size_t)(by * 256 + (tid >> 3)) * (K_DIM * 2) + kbo;
  const char* srcB = (const char*)Bt + (size_t)(bx * 256 + (tid >> 3)) * (K_DIM * 2) + kbo;
  const int stgoff = tid * 16;

  // fragment read bases: addr = ((row<<7)+kb) ^ ((row&7)<<4); kh1 = ^64; mi-hi = +8192; +2048/row16
  const int R0A = wr * 128 + r4;
  const int R0B = wc * 64 + r4;
  const int aoff = ((R0A << 7) + kb) ^ ((R0A & 7) << 4);
  const int boff = ((R0B << 7) + kb) ^ ((R0B & 7) << 4);

  f32x4 acc[8][4];
  const f32x4 z = {0.f, 0.f, 0.f, 0.f};
#pragma unroll
  for (int mi = 0; mi < 8; ++mi)
#pragma unroll
    for (int ni = 0; ni < 4; ++ni) acc[mi][ni] = z;

  // ---- prologue: tile0 full (8 loads) + tile1 B j0,j1 ----
#pragma unroll
  for (int j = 0; j < 4; ++j) GL(srcA + j * 524288, A0 + j * 8192 + stgoff);
#pragma unroll
  for (int j = 0; j < 4; ++j) GL(srcB + j * 524288, B0 + j * 8192 + stgoff);
#pragma unroll
  for (int j = 0; j < 2; ++j) GL(srcB + 128 + j * 524288, B1 + j * 8192 + stgoff);
  asm volatile("s_waitcnt vmcnt(2)" ::: "memory");
  BAR_OUT();

  bf16x8 af[4], bf[4];

  for (int J = 0; J < NITER; ++J) {
    const bool nl = (J < NITER - 1);
    const long ko1 = (long)(2 * J + 1) * 128;   // odd tile byte-col
    const long ko2 = ko1 + 128;                 // tile 2J+2
    const long ko3 = ko1 + 256;                 // tile 2J+3

    // ===== P0: tile2J kh0 lo =====
    RD_A4(A0 + aoff);
    RD_B4(B0 + boff);
    GL(srcB + ko1 + 2 * 524288, B1 + 2 * 8192 + stgoff);
    GL(srcB + ko1 + 3 * 524288, B1 + 3 * 8192 + stgoff);
    BAR_IN();
    __builtin_amdgcn_s_setprio(1); MFMA16(0); __builtin_amdgcn_s_setprio(0);
    VM4();
    BAR_OUT();

    // ===== P1: tile2J kh0 hi =====
    RD_A4(A0 + aoff + 8192);
    GL(srcA + ko1 + 0 * 524288, A1 + 0 * 8192 + stgoff);
    GL(srcA + ko1 + 2 * 524288, A1 + 2 * 8192 + stgoff);
    BAR_IN();
    __builtin_amdgcn_s_setprio(1); MFMA16(4); __builtin_amdgcn_s_setprio(0);
    BAR_OUT();

    // ===== P2: tile2J kh1 lo =====
    RD_A4(A0 + (aoff ^ 64));
    RD_B4(B0 + (boff ^ 64));
    GL(srcA + ko1 + 1 * 524288, A1 + 1 * 8192 + stgoff);
    GL(srcA + ko1 + 3 * 524288, A1 + 3 * 8192 + stgoff);
    BAR_IN();
    __builtin_amdgcn_s_setprio(1); MFMA16(0); __builtin_amdgcn_s_setprio(0);
    BAR_OUT();

    // ===== P3: tile2J kh1 hi =====
    RD_A4(A0 + (aoff ^ 64) + 8192);
    if (nl) {
      GL(srcB + ko2 + 0 * 524288, B0 + 0 * 8192 + stgoff);
      GL(srcB + ko2 + 1 * 524288, B0 + 1 * 8192 + stgoff);
    }
    BAR_IN();
    __builtin_amdgcn_s_setprio(1); MFMA16(4); __builtin_amdgcn_s_setprio(0);
    if (nl) VM4();
    else    asm volatile("s_waitcnt vmcnt(0)" ::: "memory");
    BAR_OUT();

    // ===== P4: tile2J+1 kh0 lo =====
    RD_A4(A1 + aoff);
    RD_B4(B1 + boff);
    if (nl) {
      GL(srcB + ko2 + 2 * 524288, B0 + 2 * 8192 + stgoff);
      GL(srcB + ko2 + 3 * 524288, B0 + 3 * 8192 + stgoff);
    }
    BAR_IN();
    __builtin_amdgcn_s_setprio(1); MFMA16(0); __builtin_amdgcn_s_setprio(0);
    VM4();
    BAR_OUT();

    // ===== P5: tile2J+1 kh0 hi =====
    RD_A4(A1 + aoff + 8192);
    if (nl) {
      GL(srcA + ko2 + 0 * 524288, A0 + 0 * 8192 + stgoff);
      GL(srcA + ko2 + 2 * 524288, A0 + 2 * 8192 + stgoff);
    }
    BAR_IN();
    __builtin_amdgcn_s_setprio(1); MFMA16(4); __builtin_amdgcn_s_setprio(0);
    BAR_OUT();

    // ===== P6: tile2J+1 kh1 lo =====
    RD_A4(A1 + (aoff ^ 64));
    RD_B4(B1 + (boff ^ 64));
    if (nl) {
      GL(srcA + ko2 + 1 * 524288, A0 + 1 * 8192 + stgoff);
      GL(srcA + ko2 + 3 * 524288, A0 + 3 * 8192 + stgoff);
    }
    BAR_IN();
    __builtin_amdgcn_s_setprio(1); MFMA16(0); __builtin_amdgcn_s_setprio(0);
    BAR_OUT();

    // ===== P7: tile2J+1 kh1 hi =====
    RD_A4(A1 + (aoff ^ 64) + 8192);
    if (nl) {
      GL(srcB + ko3 + 0 * 524288, B1 + 0 * 8192 + stgoff);
      GL(srcB + ko3 + 1 * 524288, B1 + 1 * 8192 + stgoff);
    }
    BAR_IN();
    __builtin_amdgcn_s_setprio(1); MFMA16(4); __builtin_amdgcn_s_setprio(0);
    VM4();
    BAR_OUT();
  }

  // ---- epilogue: C/D layout col=l&15, row=(l>>4)*4+reg ----
  const int row0 = by * 256 + wr * 128 + ((l >> 4) << 2);
  const int col0 = bx * 256 + wc * 64 + r4;
#pragma unroll
  for (int ni = 0; ni < 4; ++ni) {
    const int col = col0 + ni * 16;
    const float bv = bias[col];
#pragma unroll
    for (int mi = 0; mi < 8; ++mi) {
#pragma unroll
      for (int r = 0; r < 4; ++r)
        C[(size_t)(row0 + mi * 16 + r) * N_DIM + col] = acc[mi][ni][r] + bv;
    }
  }
}

// ---------------- fallback ----------------
__global__ void k_fallback(const float* __restrict__ x, const float* __restrict__ scales,
                           const float* __restrict__ bias, const int* __restrict__ w,
                           const int* __restrict__ ci, float* __restrict__ out) {
  const int n = blockIdx.x * 256 + threadIdx.x;
  const int m0 = blockIdx.y * 32;
  float acc[32];
#pragma unroll
  for (int i = 0; i < 32; ++i) acc[i] = 0.f;
  for (int k = 0; k < K_DIM; ++k) {
    int c = ci[k];
    float wv = (float)w[(long)k * N_DIM + n] * scales[(k >> 7) * N_DIM + n];
#pragma unroll 8
    for (int mm = 0; mm < 32; ++mm)
      acc[mm] += x[(long)(m0 + mm) * K_DIM + c] * wv;
  }
  float bv = bias[n];
  for (int mm = 0; mm < 32; ++mm)
    out[(long)(m0 + mm) * N_DIM + n] = acc[mm] + bv;
}

extern "C" void kernel_launch(void* const* d_in, const int* in_sizes, int n_in,
                              void* d_out, int out_size, void* d_ws, size_t ws_size,
                              hipStream_t stream) {
  const float* x      = (const float*)d_in[0];
  const float* scales = (const float*)d_in[1];
  const float* bias   = (const float*)d_in[2];
  const int*   wq     = (const int*)d_in[3];
  const int*   ci     = (const int*)d_in[4];
  float* out = (float*)d_out;

  const size_t xb_bytes  = (size_t)M_DIM * K_DIM * 2;
  const size_t w2t_bytes = (size_t)N_DIM * K_DIM * 2;
  const size_t need = xb_bytes + w2t_bytes + (size_t)K_DIM * 4;

  if (ws_size < need) {
    k_fallback<<<dim3(N_DIM / 256, M_DIM / 32), 256, 0, stream>>>(x, scales, bias, wq, ci, out);
    return;
  }

  unsigned short* xb  = (unsigned short*)d_ws;
  unsigned short* w2t = (unsigned short*)((char*)d_ws + xb_bytes);
  int* pinv           = (int*)((char*)d_ws + xb_bytes + w2t_bytes);

  k_pinv<<<K_DIM / 256, 256, 0, stream>>>(ci, pinv);
  k_cvt<<<2048, 256, 0, stream>>>(x, xb);
  k_w2t<<<dim3(N_DIM / 64, K_DIM / 64), 256, 0, stream>>>(wq, scales, pinv, w2t);
  k_gemm<<<(M_DIM / 256) * (N_DIM / 256), 512, 0, stream>>>(xb, w2t, bias, out);
}